// Round 1
// baseline (205.047 us; speedup 1.0000x reference)
//
#include <hip/hip_runtime.h>
#include <hip/hip_bf16.h>

typedef __attribute__((ext_vector_type(8))) short bf16x8;
typedef __attribute__((ext_vector_type(4))) float f32x4;

// Problem dims (fixed by the reference setup_inputs)
#define B   4
#define CIN 128
#define COUT 256
#define H   256
#define W   256
#define HW  (H * W)          // 65536

__device__ __forceinline__ unsigned short f2bf(float f) {
  unsigned int u = __builtin_bit_cast(unsigned int, f);
  u += 0x7fff + ((u >> 16) & 1);   // round-to-nearest-even
  return (unsigned short)(u >> 16);
}

// ---------------------------------------------------------------------------
// Kernel 0: convert w_pw (COUT x CIN f32) -> bf16 row-major
// ---------------------------------------------------------------------------
__global__ void cvt_wpw(const float* __restrict__ w, unsigned short* __restrict__ o) {
  int i = blockIdx.x * 256 + threadIdx.x;
  if (i < COUT * CIN) o[i] = f2bf(w[i]);
}

// ---------------------------------------------------------------------------
// Kernel 1: depthwise 3x3, pad 1. Writes y as bf16 in layout
//   y[(b*16 + ciBlk) * HW + hw] : 8 contiguous bf16 (ci = ciBlk*8 + 0..7)
// Grid: b(4) * h(256) * wTile(4)  = 4096 blocks, 256 threads.
// Thread t: ciBlk = t>>4 (16 blocks of 8 ci), pxg = t&15; computes px
//   w = wTile*64 + j*16 + pxg for j=0..3 (strided so stores coalesce 256B).
// ---------------------------------------------------------------------------
__global__ __launch_bounds__(256) void dw_kernel(const float* __restrict__ x,
                                                 const float* __restrict__ wdw,
                                                 unsigned short* __restrict__ y) {
  int blk = blockIdx.x;
  int wt = blk & 3;
  int h  = (blk >> 2) & 255;
  int b  = blk >> 10;

  __shared__ float wl[CIN * 9];
  for (int i = threadIdx.x; i < CIN * 9; i += 256) wl[i] = wdw[i];
  __syncthreads();

  int t = threadIdx.x;
  int ciBlk = t >> 4;          // 0..15
  int pxg   = t & 15;          // 0..15
  int ciBase = ciBlk * 8;
  int wBase  = wt * 64;

  float acc[8][4];
#pragma unroll
  for (int i = 0; i < 8; ++i)
#pragma unroll
    for (int j = 0; j < 4; ++j) acc[i][j] = 0.f;

  const float* xb = x + (size_t)b * CIN * HW;
#pragma unroll
  for (int ci = 0; ci < 8; ++ci) {
    const float* xc = xb + (size_t)(ciBase + ci) * HW;
    const float* wp = &wl[(ciBase + ci) * 9];
    float w0a = wp[0], w0b = wp[1], w0c = wp[2];
    float w1a = wp[3], w1b = wp[4], w1c = wp[5];
    float w2a = wp[6], w2b = wp[7], w2c = wp[8];
#pragma unroll
    for (int dh = 0; dh < 3; ++dh) {
      int hh = h + dh - 1;
      if (hh < 0 || hh > H - 1) continue;
      const float* xr = xc + hh * W;
      float ka = (dh == 0) ? w0a : (dh == 1) ? w1a : w2a;
      float kb = (dh == 0) ? w0b : (dh == 1) ? w1b : w2b;
      float kc = (dh == 0) ? w0c : (dh == 1) ? w1c : w2c;
#pragma unroll
      for (int j = 0; j < 4; ++j) {
        int w0 = wBase + j * 16 + pxg;
        float xm = (w0 > 0)     ? xr[w0 - 1] : 0.f;
        float x0 = xr[w0];
        float xp = (w0 < W - 1) ? xr[w0 + 1] : 0.f;
        acc[ci][j] += xm * ka + x0 * kb + xp * kc;
      }
    }
  }

#pragma unroll
  for (int j = 0; j < 4; ++j) {
    int w0 = wBase + j * 16 + pxg;
    size_t base = ((size_t)(b * 16 + ciBlk) * HW + h * W + w0) * 8;
    bf16x8 v;
#pragma unroll
    for (int i = 0; i < 8; ++i) v[i] = (short)f2bf(acc[i][j]);
    *(bf16x8*)(y + base) = v;
  }
}

// ---------------------------------------------------------------------------
// Kernel 2: pointwise 1x1 as GEMM via MFMA 16x16x32 bf16.
// out[b, co, hw] = sum_ci wpw[co, ci] * y[b, ci, hw]
// Block = 4 waves; block tile = 256co x 64px. Wave w: co in [w*64, w*64+64).
// A frag (M=co x K=ci): lane holds co = base + m*16 + (l&15),
//                                  ci = kk*32 + (l>>4)*8 + e  (16B load)
// B frag (K=ci x N=px): lane holds px = base + n*16 + (l&15),
//                                  ci = kk*32 + (l>>4)*8 + e  (16B load from y layout)
// C/D: px = base + n*16 + (l&15), co = base + m*16 + (l>>4)*4 + r
// ---------------------------------------------------------------------------
__global__ __launch_bounds__(256) void pw_kernel(const unsigned short* __restrict__ y,
                                                 const unsigned short* __restrict__ wb,
                                                 float* __restrict__ out) {
  int blk = blockIdx.x;               // 4096
  int b = blk >> 10;
  int hwBase = (blk & 1023) * 64;
  int wave = threadIdx.x >> 6;
  int l    = threadIdx.x & 63;
  int l15 = l & 15, lg = l >> 4;
  int coBase = wave * 64;

  bf16x8 A[4][4];
#pragma unroll
  for (int m = 0; m < 4; ++m)
#pragma unroll
    for (int kk = 0; kk < 4; ++kk) {
      int co = coBase + m * 16 + l15;
      int ci = kk * 32 + lg * 8;
      A[m][kk] = *(const bf16x8*)(wb + co * CIN + ci);
    }

  f32x4 acc[4][4];
#pragma unroll
  for (int m = 0; m < 4; ++m)
#pragma unroll
    for (int n = 0; n < 4; ++n) acc[m][n] = (f32x4){0.f, 0.f, 0.f, 0.f};

  const unsigned short* yb = y + (size_t)b * 16 * HW * 8;
#pragma unroll
  for (int n = 0; n < 4; ++n) {
    bf16x8 Bf[4];
#pragma unroll
    for (int kk = 0; kk < 4; ++kk) {
      int ciBlk = kk * 4 + lg;
      int hw = hwBase + n * 16 + l15;
      Bf[kk] = *(const bf16x8*)(yb + ((size_t)ciBlk * HW + hw) * 8);
    }
#pragma unroll
    for (int m = 0; m < 4; ++m)
#pragma unroll
      for (int kk = 0; kk < 4; ++kk)
        acc[m][n] = __builtin_amdgcn_mfma_f32_16x16x32_bf16(A[m][kk], Bf[kk], acc[m][n], 0, 0, 0);
  }

  float* ob = out + (size_t)b * COUT * HW;
#pragma unroll
  for (int m = 0; m < 4; ++m)
#pragma unroll
    for (int n = 0; n < 4; ++n)
#pragma unroll
      for (int r = 0; r < 4; ++r) {
        int co = coBase + m * 16 + lg * 4 + r;
        int hw = hwBase + n * 16 + l15;
        ob[(size_t)co * HW + hw] = acc[m][n][r];
      }
}

extern "C" void kernel_launch(void* const* d_in, const int* in_sizes, int n_in,
                              void* d_out, int out_size, void* d_ws, size_t ws_size,
                              hipStream_t stream) {
  const float* x   = (const float*)d_in[0];
  const float* wdw = (const float*)d_in[1];
  const float* wpw = (const float*)d_in[2];
  float* out = (float*)d_out;

  // ws layout: y bf16 [B*16][HW][8] = 67,108,864 B, then wpw bf16 65,536 B
  unsigned short* y  = (unsigned short*)d_ws;
  unsigned short* wb = y + (size_t)B * CIN * HW;   // 33,554,432 elems

  cvt_wpw<<<(COUT * CIN + 255) / 256, 256, 0, stream>>>(wpw, wb);
  dw_kernel<<<B * H * (W / 64), 256, 0, stream>>>(x, wdw, y);
  pw_kernel<<<B * (HW / 64), 256, 0, stream>>>(y, wb, out);
}